// Round 7
// baseline (312.212 us; speedup 1.0000x reference)
//
#include <hip/hip_runtime.h>

// ---------------------------------------------------------------------------
// SelfAttentionBlock: B=4, N=2048, D=1024. Single-head attention, head dim 1024.
//   QKV = X @ Wqkv^T                   (8192x1024)@(3072x1024)^T
//   E_b = exp(Q_b @ K_b^T * 0.125)     bf16, fused in S-GEMM epilogue,
//                                      row sums L accumulated atomically
//   V''_b = Wout @ V_b^T               (1024x2048) per batch
//   out_b = (E_b @ V''_b^T) / L + b    fp32  ( == softmax(S)@V@Wout^T + b )
// E-GEMM and V''-GEMM fused into ONE 1536-block dispatch (R6 win).
// GEMM core: bf16 in, fp32 acc, 32x32x16 MFMA, 128x128 tile, BK=32,
// single-buffer LDS (R5 dbuf regressed), global_load_lds width-16, XOR chunk
// swizzle for coalescing (R3/R4 A/B).
// R7: __launch_bounds__(256,4) — force <=128 regs/thread for 4 blocks/CU
// (R6 was 140 regs -> 3 blocks/CU; occupancy is the latency-hiding lever).
// ---------------------------------------------------------------------------

typedef __bf16 bf16;
typedef __attribute__((ext_vector_type(8))) __bf16 bf16x8;
typedef __attribute__((ext_vector_type(4))) __bf16 bf16x4;
typedef __attribute__((ext_vector_type(16))) float f32x16;

#define BATCH 4
#define NTOK  2048
#define DIM   1024
#define MROWS (BATCH * NTOK)   // 8192
#define QKVC  (3 * DIM)        // 3072

__device__ __forceinline__ void async16(const bf16* g, bf16* l) {
  __builtin_amdgcn_global_load_lds(
      (const __attribute__((address_space(1))) void*)g,
      (__attribute__((address_space(3))) void*)l, 16, 0, 0);
}

// ---------------------------------------------------------------------------
__global__ void f32_to_bf16(const float* __restrict__ in, bf16* __restrict__ out, int n) {
  int i = (blockIdx.x * blockDim.x + threadIdx.x) * 4;
  if (i < n) {
    float4 f = *(const float4*)(in + i);
    bf16x4 o;
    o.x = (bf16)f.x; o.y = (bf16)f.y; o.z = (bf16)f.z; o.w = (bf16)f.w;
    *(bf16x4*)(out + i) = o;
  }
}

__global__ void zero_f32(float* __restrict__ p, int n) {
  int i = blockIdx.x * blockDim.x + threadIdx.x;
  if (i < n) p[i] = 0.f;
}

// ---------------------------------------------------------------------------
// GEMM core. C[i][j] = sum_k A[i][k] * B[j][k] (B^T pattern).
// 32x32x16 MFMA, 4 waves 2x2, wave 64x64 = 2x2 of 32x32.
// C/D: col=lane&31, row=(reg&3)+8*(reg>>2)+4*(lane>>5).
// ---------------------------------------------------------------------------
struct GemmCore {
  const bf16 *ga0, *ga1, *gb0, *gb1;
  int sIdx0, sIdx1;
  int wm, wn, l31, half;
};

__device__ __forceinline__ GemmCore gemm_setup(const bf16* A, const bf16* Bm,
                                               int lda, int ldb,
                                               long rowA, long rowB) {
  GemmCore g;
  const int tid = threadIdx.x;
  const int wave = tid >> 6, lane = tid & 63;
  g.wm = (wave >> 1) << 6;
  g.wn = (wave & 1) << 6;
  g.l31 = lane & 31;
  g.half = lane >> 5;
  const int srow = tid >> 2;
  const int sc   = tid & 3;
  const int scol = (sc ^ (srow & 3)) << 3;
  g.ga0 = A  + (rowA + srow)      * (long)lda + scol;
  g.ga1 = A  + (rowA + srow + 64) * (long)lda + scol;
  g.gb0 = Bm + (rowB + srow)      * (long)ldb + scol;
  g.gb1 = Bm + (rowB + srow + 64) * (long)ldb + scol;
  g.sIdx0 = srow * 32 + sc * 8;
  g.sIdx1 = (srow + 64) * 32 + sc * 8;
  return g;
}

__device__ __forceinline__ void gemm_kloop(const GemmCore& g, int K,
                                           bf16* As, bf16* Bs, f32x16 acc[2][2]) {
  const int sw = g.l31 & 3;
  for (int kt = 0; kt < K; kt += 32) {
    async16(g.ga0 + kt, As + g.sIdx0);
    async16(g.ga1 + kt, As + g.sIdx1);
    async16(g.gb0 + kt, Bs + g.sIdx0);
    async16(g.gb1 + kt, Bs + g.sIdx1);
    __syncthreads();

    bf16x8 af[2][2], bfm[2][2];
#pragma unroll
    for (int ti = 0; ti < 2; ++ti)
#pragma unroll
      for (int s = 0; s < 2; ++s)
        af[ti][s] = *(const bf16x8*)&As[(g.wm + ti * 32 + g.l31) * 32 + ((s * 2 + g.half) ^ sw) * 8];
#pragma unroll
    for (int tj = 0; tj < 2; ++tj)
#pragma unroll
      for (int s = 0; s < 2; ++s)
        bfm[tj][s] = *(const bf16x8*)&Bs[(g.wn + tj * 32 + g.l31) * 32 + ((s * 2 + g.half) ^ sw) * 8];

#pragma unroll
    for (int s = 0; s < 2; ++s)
#pragma unroll
      for (int ti = 0; ti < 2; ++ti)
#pragma unroll
        for (int tj = 0; tj < 2; ++tj)
          acc[ti][tj] = __builtin_amdgcn_mfma_f32_32x32x16_bf16(
              af[ti][s], bfm[tj][s], acc[ti][tj], 0, 0, 0);

    __syncthreads();
  }
}

// ---------------------------------------------------------------------------
// Plain GEMMs. MODE 0: store bf16. MODE 2: store fp32 v/L[row] + bias[col].
// ---------------------------------------------------------------------------
template <int MODE>
__launch_bounds__(256, 4)
__global__ void gemm_bt(const bf16* __restrict__ Aroot, const bf16* __restrict__ Broot,
                        void* __restrict__ Croot, const float* __restrict__ bias,
                        const float* __restrict__ Lroot,
                        int K, int lda, int ldb, int ldc,
                        long strideA, long strideB, long strideC) {
  const bf16* A  = Aroot + (long)blockIdx.z * strideA;
  const bf16* Bm = Broot + (long)blockIdx.z * strideB;
  __shared__ alignas(16) bf16 As[128 * 32];
  __shared__ alignas(16) bf16 Bs[128 * 32];

  const long rowA = (long)blockIdx.y * 128;
  const long rowB = (long)blockIdx.x * 128;
  GemmCore g = gemm_setup(A, Bm, lda, ldb, rowA, rowB);

  f32x16 acc[2][2] = {};
  gemm_kloop(g, K, As, Bs, acc);

  if constexpr (MODE == 0) {
    bf16* C = (bf16*)Croot + (long)blockIdx.z * strideC;
#pragma unroll
    for (int ti = 0; ti < 2; ++ti)
#pragma unroll
      for (int tj = 0; tj < 2; ++tj) {
        const long col = rowB + g.wn + tj * 32 + g.l31;
#pragma unroll
        for (int r = 0; r < 16; ++r) {
          const long row = rowA + g.wm + ti * 32 + (r & 3) + 8 * (r >> 2) + 4 * g.half;
          C[row * (long)ldc + col] = (bf16)acc[ti][tj][r];
        }
      }
  } else {
    float* C = (float*)Croot + (long)blockIdx.z * strideC;
    const float* L = Lroot + (long)blockIdx.z * NTOK;
#pragma unroll
    for (int ti = 0; ti < 2; ++ti) {
#pragma unroll
      for (int r = 0; r < 16; ++r) {
        const long row = rowA + g.wm + ti * 32 + (r & 3) + 8 * (r >> 2) + 4 * g.half;
        const float inv = 1.0f / L[row];
#pragma unroll
        for (int tj = 0; tj < 2; ++tj) {
          const long col = rowB + g.wn + tj * 32 + g.l31;
          C[row * (long)ldc + col] = acc[ti][tj][r] * inv + bias[col];
        }
      }
    }
  }
}

// ---------------------------------------------------------------------------
// Fused dispatch: z<4 -> E_b = exp(Q_b@K_b^T/8) + row-sum L (batch z);
//                 z>=4 -> V''_b = Wout @ V_b^T (batch z-4; blockIdx.y>=8 idle).
// ---------------------------------------------------------------------------
__launch_bounds__(256, 4)
__global__ void gemm_sv(const bf16* __restrict__ QKV, const bf16* __restrict__ Wout,
                        bf16* __restrict__ E, bf16* __restrict__ Vpp,
                        float* __restrict__ Lroot) {
  __shared__ alignas(16) bf16 As[128 * 32];
  __shared__ alignas(16) bf16 Bs[128 * 32];

  const int z = blockIdx.z;
  if (z < 4) {
    // ---- E-GEMM: A=Q, B=K rows of QKV batch z ----
    const bf16* A  = QKV + (long)z * NTOK * QKVC;
    const bf16* Bm = A + DIM;
    const long rowA = (long)blockIdx.y * 128;
    const long rowB = (long)blockIdx.x * 128;
    GemmCore g = gemm_setup(A, Bm, QKVC, QKVC, rowA, rowB);
    f32x16 acc[2][2] = {};
    gemm_kloop(g, DIM, As, Bs, acc);

    bf16* C = E + (long)z * NTOK * NTOK;
    float* L = Lroot + (long)z * NTOK;
#pragma unroll
    for (int ti = 0; ti < 2; ++ti) {
#pragma unroll
      for (int r = 0; r < 16; ++r) {
        const long row = rowA + g.wm + ti * 32 + (r & 3) + 8 * (r >> 2) + 4 * g.half;
        float psum = 0.f;
#pragma unroll
        for (int tj = 0; tj < 2; ++tj) {
          const long col = rowB + g.wn + tj * 32 + g.l31;
          float e = __expf(acc[ti][tj][r] * 0.125f);
          bf16 eb = (bf16)e;
          C[row * (long)NTOK + col] = eb;
          psum += (float)eb;   // sum what downstream consumes
        }
#pragma unroll
        for (int off = 16; off >= 1; off >>= 1) psum += __shfl_xor(psum, off, 64);
        if (g.l31 == 0) atomicAdd(&L[row], psum);
      }
    }
  } else {
    if (blockIdx.y >= 8) return;   // V'' output is 1024 rows = 8 row-tiles
    // ---- V''-GEMM: A=Wout (1024x1024), B=V rows of QKV batch z-4 ----
    const int b = z - 4;
    const bf16* Bm = QKV + (long)b * NTOK * QKVC + 2 * DIM;
    const long rowA = (long)blockIdx.y * 128;
    const long rowB = (long)blockIdx.x * 128;
    GemmCore g = gemm_setup(Wout, Bm, DIM, QKVC, rowA, rowB);
    f32x16 acc[2][2] = {};
    gemm_kloop(g, DIM, As, Bs, acc);

    bf16* C = Vpp + (long)b * DIM * NTOK;
#pragma unroll
    for (int ti = 0; ti < 2; ++ti)
#pragma unroll
      for (int tj = 0; tj < 2; ++tj) {
        const long col = rowB + g.wn + tj * 32 + g.l31;
#pragma unroll
        for (int r = 0; r < 16; ++r) {
          const long row = rowA + g.wm + ti * 32 + (r & 3) + 8 * (r >> 2) + 4 * g.half;
          C[row * (long)NTOK + col] = (bf16)acc[ti][tj][r];
        }
      }
  }
}

// ---------------------------------------------------------------------------
extern "C" void kernel_launch(void* const* d_in, const int* in_sizes, int n_in,
                              void* d_out, int out_size, void* d_ws, size_t ws_size,
                              hipStream_t stream) {
  const float* x      = (const float*)d_in[0];   // (4,2048,1024)
  const float* w_qkv  = (const float*)d_in[1];   // (3072,1024)
  const float* w_out  = (const float*)d_in[2];   // (1024,1024)
  const float* b_out  = (const float*)d_in[3];   // (1024,)
  float* out = (float*)d_out;                    // (4,2048,1024) fp32

  // workspace layout (bytes) — total ~120 MiB
  char* w = (char*)d_ws;
  bf16*  Xbf   = (bf16*)(w);                          // 8192*1024*2   = 16 MiB
  bf16*  Wqkvb = (bf16*)(w + 16777216);               // 3072*1024*2   =  6 MiB
  bf16*  Woutb = (bf16*)(w + 23068672);               // 1024*1024*2   =  2 MiB
  bf16*  QKV   = (bf16*)(w + 25165824);               // 8192*3072*2   = 48 MiB
  bf16*  E     = (bf16*)(w + 75497472);               // 4*2048*2048*2 = 32 MiB
  bf16*  Vpp   = (bf16*)(w + 109051904);              // 4*1024*2048*2 = 16 MiB
  float* L     = (float*)(w + 125829120);             // 4*2048*4      = 32 KiB

  // 1) fp32 -> bf16 converts + zero row-sum accumulator
  f32_to_bf16<<<(MROWS * DIM / 4 + 255) / 256, 256, 0, stream>>>(x, Xbf, MROWS * DIM);
  f32_to_bf16<<<(QKVC * DIM / 4 + 255) / 256, 256, 0, stream>>>(w_qkv, Wqkvb, QKVC * DIM);
  f32_to_bf16<<<(DIM * DIM / 4 + 255) / 256, 256, 0, stream>>>(w_out, Woutb, DIM * DIM);
  zero_f32<<<(BATCH * NTOK + 255) / 256, 256, 0, stream>>>(L, BATCH * NTOK);

  // 2) QKV = X @ Wqkv^T -> bf16 (8192 x 3072)
  gemm_bt<0><<<dim3(QKVC / 128, MROWS / 128, 1), 256, 0, stream>>>(
      Xbf, Wqkvb, QKV, nullptr, nullptr, DIM, DIM, DIM, QKVC, 0, 0, 0);

  // 3) fused: E_b = exp(Q_b@K_b^T/8) + L row-sums  AND  V''_b = Wout @ V_b^T
  gemm_sv<<<dim3(NTOK / 128, NTOK / 128, 2 * BATCH), 256, 0, stream>>>(
      QKV, Woutb, E, Vpp, L);

  // 4) out_b = (E_b @ V''_b^T) / L + b_out -> fp32 (2048 x 1024 per batch)
  gemm_bt<2><<<dim3(DIM / 128, NTOK / 128, BATCH), 256, 0, stream>>>(
      E, Vpp, out, b_out, L, NTOK, NTOK, NTOK, DIM,
      (long)NTOK * NTOK, (long)DIM * NTOK, (long)NTOK * DIM);
}

// Round 8
// 267.930 us; speedup vs baseline: 1.1653x; 1.1653x over previous
//
#include <hip/hip_runtime.h>

// ---------------------------------------------------------------------------
// SelfAttentionBlock: B=4, N=2048, D=1024. Single-head attention, head dim 1024.
//   QKV = X @ Wqkv^T                   (8192x1024)@(3072x1024)^T
//   E_b = exp(Q_b @ K_b^T * 0.125)     bf16, fused in S-GEMM epilogue,
//                                      row sums L accumulated atomically
//   V''_b = Wout @ V_b^T               (1024x2048) per batch
//   out_b = (E_b @ V''_b^T) / L + b    fp32  ( == softmax(S)@V@Wout^T + b )
// E-GEMM and V''-GEMM fused into ONE 1536-block dispatch (R6 win).
// GEMM core: bf16 in, fp32 acc, 32x32x16 MFMA, 128x128 tile,
// R8: BK=64 (halve barrier-drain count; 16 MFMA per wave-iter), 32 KB
// single-buffer LDS, 8-chunk XOR swizzle c^(r&7). NO launch_bounds occupancy
// cap (R7's reg squeeze to 56 VGPR regressed — starved staging ILP).
// ---------------------------------------------------------------------------

typedef __bf16 bf16;
typedef __attribute__((ext_vector_type(8))) __bf16 bf16x8;
typedef __attribute__((ext_vector_type(4))) __bf16 bf16x4;
typedef __attribute__((ext_vector_type(16))) float f32x16;

#define BATCH 4
#define NTOK  2048
#define DIM   1024
#define MROWS (BATCH * NTOK)   // 8192
#define QKVC  (3 * DIM)        // 3072

__device__ __forceinline__ void async16(const bf16* g, bf16* l) {
  __builtin_amdgcn_global_load_lds(
      (const __attribute__((address_space(1))) void*)g,
      (__attribute__((address_space(3))) void*)l, 16, 0, 0);
}

// ---------------------------------------------------------------------------
// one prep kernel: three fp32->bf16 converts + L zero (saves launch gaps)
// ---------------------------------------------------------------------------
__device__ __forceinline__ void cvt4(const float* in, bf16* out, int i4) {
  float4 f = *(const float4*)(in + i4 * 4);
  bf16x4 o;
  o.x = (bf16)f.x; o.y = (bf16)f.y; o.z = (bf16)f.z; o.w = (bf16)f.w;
  *(bf16x4*)(out + i4 * 4) = o;
}

__global__ void prep(const float* __restrict__ x, const float* __restrict__ wqkv,
                     const float* __restrict__ wout,
                     bf16* __restrict__ Xbf, bf16* __restrict__ Wqkvb,
                     bf16* __restrict__ Woutb, float* __restrict__ L) {
  const int nx = MROWS * DIM / 4, nq = QKVC * DIM / 4, nw = DIM * DIM / 4;
  const int nl = BATCH * NTOK / 4;
  int i = blockIdx.x * blockDim.x + threadIdx.x;
  if (i < nx) cvt4(x, Xbf, i);
  else if (i < nx + nq) cvt4(wqkv, Wqkvb, i - nx);
  else if (i < nx + nq + nw) cvt4(wout, Woutb, i - nx - nq);
  else if (i < nx + nq + nw + nl) {
    float4 z = {0.f, 0.f, 0.f, 0.f};
    *(float4*)(L + (i - nx - nq - nw) * 4) = z;
  }
}

// ---------------------------------------------------------------------------
// GEMM core. C[i][j] = sum_k A[i][k] * B[j][k] (B^T pattern). BK=64.
// 32x32x16 MFMA, 4 waves 2x2, wave 64x64 = 2x2 of 32x32.
// A-frag: A[m=lane&31][k=8*(lane>>5)+e]. C/D: col=lane&31,
// row=(reg&3)+8*(reg>>2)+4*(lane>>5).
// LDS tile [128 rows][64 k], 128B rows = 8 chunks; slot c of row r holds
// global chunk c^(r&7). Staging: tid -> row=tid>>3 (+32*seg), slot=tid&7;
// 8 lanes/row cover one contiguous 128B global segment -> coalesced, and
// LDS dst stays linear tid*16 (wave-uniform base + lane*16).
// ---------------------------------------------------------------------------
struct GemmCore {
  const bf16 *ga[4], *gb[4];
  int sIdx[4];
  int wm, wn, l31, half;
};

__device__ __forceinline__ GemmCore gemm_setup(const bf16* A, const bf16* Bm,
                                               int lda, int ldb,
                                               long rowA, long rowB) {
  GemmCore g;
  const int tid = threadIdx.x;
  const int wave = tid >> 6, lane = tid & 63;
  g.wm = (wave >> 1) << 6;
  g.wn = (wave & 1) << 6;
  g.l31 = lane & 31;
  g.half = lane >> 5;
  const int srow = tid >> 3;               // 0..31
  const int sc   = tid & 7;                // physical slot
  const int scol = (sc ^ (srow & 7)) << 3; // swizzled global chunk * 8
#pragma unroll
  for (int seg = 0; seg < 4; ++seg) {
    g.ga[seg] = A  + (rowA + srow + 32 * seg) * (long)lda + scol;
    g.gb[seg] = Bm + (rowB + srow + 32 * seg) * (long)ldb + scol;
    g.sIdx[seg] = (srow + 32 * seg) * 64 + sc * 8;
  }
  return g;
}

__device__ __forceinline__ void gemm_kloop(const GemmCore& g, int K,
                                           bf16* As, bf16* Bs, f32x16 acc[2][2]) {
  const int sw = g.l31 & 7;
  for (int kt = 0; kt < K; kt += 64) {
#pragma unroll
    for (int seg = 0; seg < 4; ++seg) {
      async16(g.ga[seg] + kt, As + g.sIdx[seg]);
      async16(g.gb[seg] + kt, Bs + g.sIdx[seg]);
    }
    __syncthreads();

    bf16x8 af[2][4], bfm[2][4];
#pragma unroll
    for (int ti = 0; ti < 2; ++ti)
#pragma unroll
      for (int s = 0; s < 4; ++s)
        af[ti][s] = *(const bf16x8*)&As[(g.wm + ti * 32 + g.l31) * 64 + ((s * 2 + g.half) ^ sw) * 8];
#pragma unroll
    for (int tj = 0; tj < 2; ++tj)
#pragma unroll
      for (int s = 0; s < 4; ++s)
        bfm[tj][s] = *(const bf16x8*)&Bs[(g.wn + tj * 32 + g.l31) * 64 + ((s * 2 + g.half) ^ sw) * 8];

#pragma unroll
    for (int s = 0; s < 4; ++s)
#pragma unroll
      for (int ti = 0; ti < 2; ++ti)
#pragma unroll
        for (int tj = 0; tj < 2; ++tj)
          acc[ti][tj] = __builtin_amdgcn_mfma_f32_32x32x16_bf16(
              af[ti][s], bfm[tj][s], acc[ti][tj], 0, 0, 0);

    __syncthreads();
  }
}

// ---------------------------------------------------------------------------
// Plain GEMMs. MODE 0: store bf16. MODE 2: store fp32 v/L[row] + bias[col].
// ---------------------------------------------------------------------------
template <int MODE>
__launch_bounds__(256)
__global__ void gemm_bt(const bf16* __restrict__ Aroot, const bf16* __restrict__ Broot,
                        void* __restrict__ Croot, const float* __restrict__ bias,
                        const float* __restrict__ Lroot,
                        int K, int lda, int ldb, int ldc,
                        long strideA, long strideB, long strideC) {
  const bf16* A  = Aroot + (long)blockIdx.z * strideA;
  const bf16* Bm = Broot + (long)blockIdx.z * strideB;
  __shared__ alignas(16) bf16 As[128 * 64];
  __shared__ alignas(16) bf16 Bs[128 * 64];

  const long rowA = (long)blockIdx.y * 128;
  const long rowB = (long)blockIdx.x * 128;
  GemmCore g = gemm_setup(A, Bm, lda, ldb, rowA, rowB);

  f32x16 acc[2][2] = {};
  gemm_kloop(g, K, As, Bs, acc);

  if constexpr (MODE == 0) {
    bf16* C = (bf16*)Croot + (long)blockIdx.z * strideC;
#pragma unroll
    for (int ti = 0; ti < 2; ++ti)
#pragma unroll
      for (int tj = 0; tj < 2; ++tj) {
        const long col = rowB + g.wn + tj * 32 + g.l31;
#pragma unroll
        for (int r = 0; r < 16; ++r) {
          const long row = rowA + g.wm + ti * 32 + (r & 3) + 8 * (r >> 2) + 4 * g.half;
          C[row * (long)ldc + col] = (bf16)acc[ti][tj][r];
        }
      }
  } else {
    float* C = (float*)Croot + (long)blockIdx.z * strideC;
    const float* L = Lroot + (long)blockIdx.z * NTOK;
#pragma unroll
    for (int ti = 0; ti < 2; ++ti) {
#pragma unroll
      for (int r = 0; r < 16; ++r) {
        const long row = rowA + g.wm + ti * 32 + (r & 3) + 8 * (r >> 2) + 4 * g.half;
        const float inv = 1.0f / L[row];
#pragma unroll
        for (int tj = 0; tj < 2; ++tj) {
          const long col = rowB + g.wn + tj * 32 + g.l31;
          C[row * (long)ldc + col] = acc[ti][tj][r] * inv + bias[col];
        }
      }
    }
  }
}

// ---------------------------------------------------------------------------
// Fused dispatch: z<4 -> E_b = exp(Q_b@K_b^T/8) + row-sum L (batch z);
//                 z>=4 -> V''_b = Wout @ V_b^T (batch z-4; blockIdx.y>=8 idle).
// ---------------------------------------------------------------------------
__launch_bounds__(256)
__global__ void gemm_sv(const bf16* __restrict__ QKV, const bf16* __restrict__ Wout,
                        bf16* __restrict__ E, bf16* __restrict__ Vpp,
                        float* __restrict__ Lroot) {
  __shared__ alignas(16) bf16 As[128 * 64];
  __shared__ alignas(16) bf16 Bs[128 * 64];

  const int z = blockIdx.z;
  if (z < 4) {
    // ---- E-GEMM: A=Q, B=K rows of QKV batch z ----
    const bf16* A  = QKV + (long)z * NTOK * QKVC;
    const bf16* Bm = A + DIM;
    const long rowA = (long)blockIdx.y * 128;
    const long rowB = (long)blockIdx.x * 128;
    GemmCore g = gemm_setup(A, Bm, QKVC, QKVC, rowA, rowB);
    f32x16 acc[2][2] = {};
    gemm_kloop(g, DIM, As, Bs, acc);

    bf16* C = E + (long)z * NTOK * NTOK;
    float* L = Lroot + (long)z * NTOK;
#pragma unroll
    for (int ti = 0; ti < 2; ++ti) {
#pragma unroll
      for (int r = 0; r < 16; ++r) {
        const long row = rowA + g.wm + ti * 32 + (r & 3) + 8 * (r >> 2) + 4 * g.half;
        float psum = 0.f;
#pragma unroll
        for (int tj = 0; tj < 2; ++tj) {
          const long col = rowB + g.wn + tj * 32 + g.l31;
          float e = __expf(acc[ti][tj][r] * 0.125f);
          bf16 eb = (bf16)e;
          C[row * (long)NTOK + col] = eb;
          psum += (float)eb;   // sum what downstream consumes
        }
#pragma unroll
        for (int off = 16; off >= 1; off >>= 1) psum += __shfl_xor(psum, off, 64);
        if (g.l31 == 0) atomicAdd(&L[row], psum);
      }
    }
  } else {
    if (blockIdx.y >= 8) return;   // V'' output is 1024 rows = 8 row-tiles
    // ---- V''-GEMM: A=Wout (1024x1024), B=V rows of QKV batch z-4 ----
    const int b = z - 4;
    const bf16* Bm = QKV + (long)b * NTOK * QKVC + 2 * DIM;
    const long rowA = (long)blockIdx.y * 128;
    const long rowB = (long)blockIdx.x * 128;
    GemmCore g = gemm_setup(Wout, Bm, DIM, QKVC, rowA, rowB);
    f32x16 acc[2][2] = {};
    gemm_kloop(g, DIM, As, Bs, acc);

    bf16* C = Vpp + (long)b * DIM * NTOK;
#pragma unroll
    for (int ti = 0; ti < 2; ++ti)
#pragma unroll
      for (int tj = 0; tj < 2; ++tj) {
        const long col = rowB + g.wn + tj * 32 + g.l31;
#pragma unroll
        for (int r = 0; r < 16; ++r) {
          const long row = rowA + g.wm + ti * 32 + (r & 3) + 8 * (r >> 2) + 4 * g.half;
          C[row * (long)NTOK + col] = (bf16)acc[ti][tj][r];
        }
      }
  }
}

// ---------------------------------------------------------------------------
extern "C" void kernel_launch(void* const* d_in, const int* in_sizes, int n_in,
                              void* d_out, int out_size, void* d_ws, size_t ws_size,
                              hipStream_t stream) {
  const float* x      = (const float*)d_in[0];   // (4,2048,1024)
  const float* w_qkv  = (const float*)d_in[1];   // (3072,1024)
  const float* w_out  = (const float*)d_in[2];   // (1024,1024)
  const float* b_out  = (const float*)d_in[3];   // (1024,)
  float* out = (float*)d_out;                    // (4,2048,1024) fp32

  // workspace layout (bytes) — total ~120 MiB
  char* w = (char*)d_ws;
  bf16*  Xbf   = (bf16*)(w);                          // 8192*1024*2   = 16 MiB
  bf16*  Wqkvb = (bf16*)(w + 16777216);               // 3072*1024*2   =  6 MiB
  bf16*  Woutb = (bf16*)(w + 23068672);               // 1024*1024*2   =  2 MiB
  bf16*  QKV   = (bf16*)(w + 25165824);               // 8192*3072*2   = 48 MiB
  bf16*  E     = (bf16*)(w + 75497472);               // 4*2048*2048*2 = 32 MiB
  bf16*  Vpp   = (bf16*)(w + 109051904);              // 4*1024*2048*2 = 16 MiB
  float* L     = (float*)(w + 125829120);             // 4*2048*4      = 32 KiB

  // 1) one prep dispatch: converts + L zero
  {
    const int n4 = MROWS * DIM / 4 + QKVC * DIM / 4 + DIM * DIM / 4 + BATCH * NTOK / 4;
    prep<<<(n4 + 255) / 256, 256, 0, stream>>>(x, w_qkv, w_out, Xbf, Wqkvb, Woutb, L);
  }

  // 2) QKV = X @ Wqkv^T -> bf16 (8192 x 3072)
  gemm_bt<0><<<dim3(QKVC / 128, MROWS / 128, 1), 256, 0, stream>>>(
      Xbf, Wqkvb, QKV, nullptr, nullptr, DIM, DIM, DIM, QKVC, 0, 0, 0);

  // 3) fused: E_b = exp(Q_b@K_b^T/8) + L row-sums  AND  V''_b = Wout @ V_b^T
  gemm_sv<<<dim3(NTOK / 128, NTOK / 128, 2 * BATCH), 256, 0, stream>>>(
      QKV, Woutb, E, Vpp, L);

  // 4) out_b = (E_b @ V''_b^T) / L + b_out -> fp32 (2048 x 1024 per batch)
  gemm_bt<2><<<dim3(DIM / 128, NTOK / 128, BATCH), 256, 0, stream>>>(
      E, Vpp, out, b_out, L, NTOK, NTOK, NTOK, DIM,
      (long)NTOK * NTOK, (long)DIM * NTOK, (long)NTOK * DIM);
}